// Round 1
// 585.283 us; speedup vs baseline: 1.0726x; 1.0726x over previous
//
#include <hip/hip_runtime.h>

#define MROWS 8192
#define NCOLS 128
#define KSTEP 128
#define LDT   136   // LDS row stride in bf16 elems: 272 B -> bank stride 4 (2-way, free), 16B-aligned

using f32x4  = __attribute__((ext_vector_type(4))) float;
using bf16x8 = __attribute__((ext_vector_type(8))) short;
using u32x4  = __attribute__((ext_vector_type(4))) unsigned int;
using u32x2  = __attribute__((ext_vector_type(2))) unsigned int;

__device__ __forceinline__ unsigned short f2bf(float f) {
    unsigned int u = __float_as_uint(f);
    u += 0x7fffu + ((u >> 16) & 1u);   // RNE
    return (unsigned short)(u >> 16);
}
__device__ __forceinline__ unsigned int pk2(float a, float b) {
    return (unsigned int)f2bf(a) | ((unsigned int)f2bf(b) << 16);
}

// C[M,128] = A[M,K](fp32) @ B[K,128], with B stored transposed bf16: Bt[c][k], row stride ldb.
// One block owns 32 output rows x all 128 cols over the FULL K (no split-K, no partials).
// 512 threads = 8 waves in a 2(m) x 4(n) grid; each wave: 16 rows x 32 cols -> acc = 2 f32x4.
// Pipeline: 2-deep register prefetch -> LDS single-buffer with 2 barriers per 128-wide K-step;
// loads are issued ~1.5 iterations (>2000 cyc) before their LDS store, hiding HBM latency.
// OUTMODE 0: bf16 transposed   out[c][r]              (Tt)
// OUTMODE 1: bf16 transposed   out[c][r] = v*filt[r]  (Rt, filt fused)
// OUTMODE 2: fp32 row-major    out[r][c]              (final output)
template <int OUTMODE>
__global__ __launch_bounds__(512, 2) void gemm_tall(
    const float* __restrict__ A,
    const unsigned short* __restrict__ Bt,
    void* __restrict__ out,
    const float* __restrict__ filt,
    int Kdim, int ldb)
{
    __shared__ __align__(16) unsigned short As[32 * LDT];
    __shared__ __align__(16) unsigned short Bs[128 * LDT];

    const int tid  = threadIdx.x;
    const int lane = tid & 63;
    const int w    = tid >> 6;
    const int wm   = (w >> 2) * 16;   // 0 / 16
    const int wn   = (w & 3) * 32;    // 0 / 32 / 64 / 96
    const int lrow = lane & 15;
    const int lq   = lane >> 4;
    const int m0   = blockIdx.x * 32;

    // coalesced staging decomposition
    const int arow = tid >> 4;          // 0..31, 16 thr/row, 8 fp32 each (512 B contig per row)
    const int ak   = (tid & 15) * 8;
    const int brow = tid >> 2;          // 0..127, 4 thr/row, 32 bf16 each
    const int bk   = (tid & 3) * 32;

    const float*          Ap = A  + (size_t)(m0 + arow) * Kdim + ak;
    const unsigned short* Bp = Bt + (size_t)brow * ldb + bk;

    f32x4 a0[2], a1[2];
    u32x4 b0[4], b1[4];

#define LDG(a, b, k0) do { \
        a[0] = *(const f32x4*)(Ap + (k0));      \
        a[1] = *(const f32x4*)(Ap + (k0) + 4);  \
        const unsigned short* bp_ = Bp + (k0);  \
        b[0] = *(const u32x4*)(bp_);            \
        b[1] = *(const u32x4*)(bp_ + 8);        \
        b[2] = *(const u32x4*)(bp_ + 16);       \
        b[3] = *(const u32x4*)(bp_ + 24);       \
    } while (0)

#define STG(a, b) do { \
        u32x4 av_;                                   \
        av_.x = pk2(a[0].x, a[0].y);                 \
        av_.y = pk2(a[0].z, a[0].w);                 \
        av_.z = pk2(a[1].x, a[1].y);                 \
        av_.w = pk2(a[1].z, a[1].w);                 \
        *(u32x4*)&As[arow * LDT + ak] = av_;         \
        *(u32x4*)&Bs[brow * LDT + bk]      = b[0];   \
        *(u32x4*)&Bs[brow * LDT + bk + 8]  = b[1];   \
        *(u32x4*)&Bs[brow * LDT + bk + 16] = b[2];   \
        *(u32x4*)&Bs[brow * LDT + bk + 24] = b[3];   \
    } while (0)

    f32x4 acc0 = {0.f, 0.f, 0.f, 0.f};
    f32x4 acc1 = {0.f, 0.f, 0.f, 0.f};

    auto COMPUTE = [&]() {
#pragma unroll
        for (int kk = 0; kk < 4; ++kk) {
            const int ko = kk * 32 + lq * 8;
            bf16x8 af  = *(bf16x8*)&As[(wm + lrow) * LDT + ko];
            bf16x8 bf0 = *(bf16x8*)&Bs[(wn + lrow) * LDT + ko];
            bf16x8 bf1 = *(bf16x8*)&Bs[(wn + 16 + lrow) * LDT + ko];
            acc0 = __builtin_amdgcn_mfma_f32_16x16x32_bf16(af, bf0, acc0, 0, 0, 0);
            acc1 = __builtin_amdgcn_mfma_f32_16x16x32_bf16(af, bf1, acc1, 0, 0, 0);
        }
    };

    const int iters = Kdim / KSTEP;     // 64 (big GEMMs) or 2 (GEMM1) — always even
    LDG(a0, b0, 0);
    LDG(a1, b1, KSTEP);
    STG(a0, b0);
    __syncthreads();

    for (int it = 0; it < iters; it += 2) {
        if (it + 2 < iters) LDG(a0, b0, (it + 2) * KSTEP);   // prefetch step it+2 (used 1.5 iters later)
        COMPUTE();                                           // step it
        __syncthreads();
        STG(a1, b1);                                         // step it+1 -> LDS
        __syncthreads();
        if (it + 3 < iters) LDG(a1, b1, (it + 3) * KSTEP);   // prefetch step it+3
        COMPUTE();                                           // step it+1
        if (it + 2 < iters) {
            __syncthreads();
            STG(a0, b0);                                     // step it+2 -> LDS
            __syncthreads();
        }
    }
#undef LDG
#undef STG

    const int r = m0 + wm + lq * 4;
    if (OUTMODE == 2) {
        float* O = (float*)out;
#pragma unroll
        for (int nt = 0; nt < 2; ++nt) {
            const int c = wn + nt * 16 + lrow;
            const f32x4 v = nt ? acc1 : acc0;
#pragma unroll
            for (int e = 0; e < 4; ++e)
                O[(size_t)(r + e) * NCOLS + c] = v[e];
        }
    } else {
        unsigned short* O = (unsigned short*)out;
        f32x4 v0 = acc0, v1 = acc1;
        if (OUTMODE == 1) {
            const f32x4 fl = *(const f32x4*)&filt[r];   // r is 16B-aligned multiple of 4
            v0 *= fl;
            v1 *= fl;
        }
        u32x2 o;
        o.x = pk2(v0.x, v0.y); o.y = pk2(v0.z, v0.w);
        *(u32x2*)&O[(size_t)(wn + lrow) * MROWS + r] = o;
        o.x = pk2(v1.x, v1.y); o.y = pk2(v1.z, v1.w);
        *(u32x2*)&O[(size_t)(wn + 16 + lrow) * MROWS + r] = o;
    }
}

// Wt[c][k] = bf16(W[k][c]) : 256x128 fp32 -> transposed bf16
__global__ void convert_w(const float* __restrict__ W, unsigned short* __restrict__ Wt) {
    int idx = blockIdx.x * 256 + threadIdx.x;   // 32768 total
    int k = idx >> 7, c = idx & 127;
    Wt[c * 256 + k] = f2bf(W[idx]);
}

extern "C" void kernel_launch(void* const* d_in, const int* in_sizes, int n_in,
                              void* d_out, int out_size, void* d_ws, size_t ws_size,
                              hipStream_t stream) {
    const float* features     = (const float*)d_in[0];
    const float* wavelets     = (const float*)d_in[1];
    const float* wavelets_inv = (const float*)d_in[2];
    const float* W            = (const float*)d_in[3];
    const float* filt         = (const float*)d_in[4];
    float* outp = (float*)d_out;

    char* ws = (char*)d_ws;
    unsigned short* Tt = (unsigned short*)ws;                              // 2 MB  Tt[c][r]
    unsigned short* Rt = (unsigned short*)(ws + (size_t)2 * 1024 * 1024);  // 2 MB  Rt[c][r]
    unsigned short* Wt = (unsigned short*)(ws + (size_t)4 * 1024 * 1024);  // 64 KB Wt[c][k]

    // 1) W -> Wt (bf16, transposed)
    convert_w<<<128, 256, 0, stream>>>(W, Wt);
    // 2) Tt = (features @ W)^T          full-K, direct bf16 transposed output
    gemm_tall<0><<<256, 512, 0, stream>>>(features,     Wt, (void*)Tt,   nullptr, 256,  256);
    // 3) Rt = (filt ⊙ (wavelets_inv @ T))^T   full-K, filt fused in epilogue
    gemm_tall<1><<<256, 512, 0, stream>>>(wavelets_inv, Tt, (void*)Rt,   filt,    8192, 8192);
    // 4) out = wavelets @ R             full-K, fp32 row-major output
    gemm_tall<2><<<256, 512, 0, stream>>>(wavelets,     Rt, (void*)outp, nullptr, 8192, 8192);
}